// Round 13
// baseline (313.194 us; speedup 1.0000x reference)
//
#include <hip/hip_runtime.h>
#include <hip/hip_bf16.h>
#include <float.h>

typedef _Float16 f16;
typedef __attribute__((ext_vector_type(8))) _Float16 half8;
typedef __attribute__((ext_vector_type(4))) float floatx4;

// Problem constants
#define DIM   128
#define HW    4096
#define NPOS  131072
#define K     512
#define ZSTRIDE_B 524288

// Output layout (floats)
#define Q_OFF     0
#define LOSS_OFF  16777216
#define IDX_OFF   16777217
#define NEMB_OFF  16908289
#define NCS_OFF   16973825
#define NEA_OFF   16974337

// Workspace layout (floats): LOSS+E2+ENC+ESUM contiguous -> one memset.
// EHI/ELO past ESUM, 16B-aligned.
#define WS_LOSS  0
#define WS_E2    2
#define WS_ENC   514
#define WS_ESUM  1026          // 65536 floats, ends at 66562
#define WS_ZERO_COUNT 66562    // floats zeroed by the single upfront memset
#define WS_EHI   66564         // f16[K*DIM] = 32768 floats; byte ofs %16 == 0
#define WS_ELO   99332         // f16[K*DIM] = 32768 floats

#define XST 136   // xs row stride (f16): 128 d + 8 pad -> 272B, 16B-aligned, 2-way banks

// ---------------------------------------------------------------------------
// k_prep (r11 vectorized): thread = (code k, d-octet o): 8 coalesced f32
// reads, ONE contiguous 16B half8 store each to hi/lo. Packed layout:
//   idx(c,d) = (g*4+dc)*512 + quad*128 + r*8 + j, d = o*8+j
//   => base = (g*4+(o>>2))*512 + (o&3)*128 + r*8.
// e2 folded: per-thread 8-term partial, 16 atomics/address (native f32).
__global__ __launch_bounds__(256) void k_prep(const float* __restrict__ emb,
                                              f16* __restrict__ ehiP,
                                              f16* __restrict__ eloP,
                                              float* __restrict__ e2) {
    int lin = blockIdx.x * 256 + threadIdx.x;   // 8192 threads
    int o = lin >> 9, k = lin & 511;            // o = d-octet 0..15
    int g = k >> 4, r = k & 15;
    half8 hh, ll;
    float s = 0.f;
    #pragma unroll
    for (int j = 0; j < 8; ++j) {
        float v = emb[(o * 8 + j) * K + k];     // coalesced (lanes = consec k)
        f16 h = (f16)v;
        f16 l = (f16)(v - (float)h);
        hh[j] = h; ll[j] = l;
        s = fmaf(v, v, s);
    }
    int base = (g * 4 + (o >> 2)) * 512 + (o & 3) * 128 + r * 8;
    *(half8*)&ehiP[base] = hh;                  // 16B store
    *(half8*)&eloP[base] = ll;                  // 16B store
    unsafeAtomicAdd(&e2[k], s);                 // 16-way contention, native
}

// ---------------------------------------------------------------------------
// k_assign v13: r12 structure + ONE-DC-LOOKAHEAD B prefetch inside the reg
// budget. Register accounting (m69 tiers: waves halve at 64/128/256 VGPR --
// we must stay <=128 for 4 waves/SIMD):
//   acc 32 + best 32 + bh/bl 16 + nbh/nbl 16 + ah/al 8 (per-t, was 32) + addr
//   ~15 = ~119. r11's version put B[4][2] fully resident (64) -> 132 -> 3
//   waves/SIMD -> 161us. This version keeps only cur+next dc (16+16).
// Mechanism: next dc's 4 B-loads (L2, ~300cy) issue BEFORE the 24 MFMAs of
// the current dc -> latency hides under MFMA issue + LDS A-reads.
// First prefetch issues before the staging barrier (overlaps drain).
// TRIPWIRES: VGPR > 128 or WRITE >> 66MB -> revert to r12.
__global__ __launch_bounds__(256, 2) void k_assign(const float* __restrict__ z,
                                                   const f16* __restrict__ ehiP,
                                                   const f16* __restrict__ eloP,
                                                   const float* __restrict__ e2,
                                                   float* __restrict__ out,
                                                   float* __restrict__ lossAcc) {
    __shared__ f16 xs_h[64 * XST];
    __shared__ f16 xs_l[64 * XST];
    __shared__ float wbD[256];
    __shared__ int   wbI[256];
    __shared__ int   bidx[64];
    __shared__ float wred[4];

    const int tid  = threadIdx.x;
    const int lane = tid & 63;
    const int wv   = tid >> 6;
    const int n0   = blockIdx.x * 64;
    const int b    = n0 >> 12;
    const int hw0  = n0 & 4095;
    const float* zb = z + b * ZSTRIDE_B + hw0;
    const int l15  = lane & 15;
    const int quad = lane >> 4;

    const half8* gh = (const half8*)ehiP;
    const half8* gl = (const half8*)eloP;

    // ---- issue cc=0/dc=0 B prefetch BEFORE staging (independent of it)
    half8 bh[2], bl[2];
    #pragma unroll
    for (int nt = 0; nt < 2; ++nt) {
        int g = wv * 2 + nt;
        bh[nt] = gh[(g * 4 + 0) * 64 + lane];
        bl[nt] = gl[(g * 4 + 0) * 64 + lane];
    }

    // ---- stage X split (64 pos x 128 d): phase 1 = issue all 32 loads,
    // phase 2 = convert + packed u32 LDS writes. Static indexing throughout.
    float sv0[16], sv1[16];
    #pragma unroll
    for (int it = 0; it < 16; ++it) {
        int lin = tid + it * 256;
        int i  = lin & 63;          // position (lanes consecutive -> coalesced)
        int dp = lin >> 6;          // d-pair 0..63
        sv0[it] = zb[(2 * dp) * HW + i];
        sv1[it] = zb[(2 * dp + 1) * HW + i];
    }
    #pragma unroll
    for (int it = 0; it < 16; ++it) {
        int lin = tid + it * 256;
        int i  = lin & 63;
        int dp = lin >> 6;
        float v0 = sv0[it], v1 = sv1[it];
        f16 h0 = (f16)v0; f16 l0 = (f16)(v0 - (float)h0);
        f16 h1 = (f16)v1; f16 l1 = (f16)(v1 - (float)h1);
        union { f16 h[2]; unsigned int u; } ph, pl;
        ph.h[0] = h0; ph.h[1] = h1;
        pl.h[0] = l0; pl.h[1] = l1;
        *(unsigned int*)&xs_h[i * XST + 2 * dp] = ph.u;
        *(unsigned int*)&xs_l[i * XST + 2 * dp] = pl.u;
    }
    __syncthreads();

    float bestD[4][4];
    int   bestI[4][4];
    #pragma unroll
    for (int t = 0; t < 4; ++t)
        #pragma unroll
        for (int r = 0; r < 4; ++r) { bestD[t][r] = FLT_MAX; bestI[t][r] = 0x7fffffff; }

    for (int cc = 0; cc < 4; ++cc) {       // 4 chunks x 128 codes
        floatx4 acc[4][2];
        #pragma unroll
        for (int t = 0; t < 4; ++t)
            #pragma unroll
            for (int nt = 0; nt < 2; ++nt) acc[t][nt] = (floatx4){0.f, 0.f, 0.f, 0.f};

        #pragma unroll
        for (int dc = 0; dc < 4; ++dc) {
            // prefetch NEXT B (next dc, or next cc's dc=0) before this dc's MFMAs
            half8 nbh[2], nbl[2];
            if (dc < 3) {
                #pragma unroll
                for (int nt = 0; nt < 2; ++nt) {
                    int g = cc * 8 + wv * 2 + nt;
                    nbh[nt] = gh[(g * 4 + dc + 1) * 64 + lane];
                    nbl[nt] = gl[(g * 4 + dc + 1) * 64 + lane];
                }
            } else if (cc < 3) {
                #pragma unroll
                for (int nt = 0; nt < 2; ++nt) {
                    int g = (cc + 1) * 8 + wv * 2 + nt;
                    nbh[nt] = gh[(g * 4 + 0) * 64 + lane];
                    nbl[nt] = gl[(g * 4 + 0) * 64 + lane];
                }
            }
            // A per t (8 live regs instead of 32), 6 MFMAs per t
            #pragma unroll
            for (int t = 0; t < 4; ++t) {
                int off = (t * 16 + l15) * XST + dc * 32 + quad * 8;
                half8 ah = *(const half8*)&xs_h[off];
                half8 al = *(const half8*)&xs_l[off];
                #pragma unroll
                for (int nt = 0; nt < 2; ++nt) {
                    acc[t][nt] = __builtin_amdgcn_mfma_f32_16x16x32_f16(ah, bh[nt], acc[t][nt], 0, 0, 0);
                    acc[t][nt] = __builtin_amdgcn_mfma_f32_16x16x32_f16(al, bh[nt], acc[t][nt], 0, 0, 0);
                    acc[t][nt] = __builtin_amdgcn_mfma_f32_16x16x32_f16(ah, bl[nt], acc[t][nt], 0, 0, 0);
                }
            }
            // rotate prefetch -> current (unrolled: pure register rename)
            #pragma unroll
            for (int nt = 0; nt < 2; ++nt) { bh[nt] = nbh[nt]; bl[nt] = nbl[nt]; }
        }
        // fold scores into best (codes ascend across cc,nt for fixed lane -> strict <)
        #pragma unroll
        for (int nt = 0; nt < 2; ++nt) {
            int c = cc * 128 + wv * 32 + nt * 16 + l15;
            float ee = e2[c];
            #pragma unroll
            for (int t = 0; t < 4; ++t)
                #pragma unroll
                for (int r = 0; r < 4; ++r) {
                    float s = fmaf(-2.f, acc[t][nt][r], ee);
                    if (s < bestD[t][r]) { bestD[t][r] = s; bestI[t][r] = c; }
                }
        }
    }

    // reduce across the 16 lanes holding different codes for the same rows
    #pragma unroll
    for (int mask = 1; mask <= 8; mask <<= 1) {
        #pragma unroll
        for (int t = 0; t < 4; ++t)
            #pragma unroll
            for (int r = 0; r < 4; ++r) {
                float od = __shfl_xor(bestD[t][r], mask, 64);
                int   oi = __shfl_xor(bestI[t][r], mask, 64);
                if (od < bestD[t][r] || (od == bestD[t][r] && oi < bestI[t][r])) {
                    bestD[t][r] = od; bestI[t][r] = oi;
                }
            }
    }
    if (l15 == 0) {
        #pragma unroll
        for (int t = 0; t < 4; ++t)
            #pragma unroll
            for (int r = 0; r < 4; ++r) {
                int m = t * 16 + quad * 4 + r;   // C layout: row=(lane>>4)*4+reg
                wbD[wv * 64 + m] = bestD[t][r];
                wbI[wv * 64 + m] = bestI[t][r];
            }
    }
    __syncthreads();
    if (tid < 64) {
        float bd = wbD[tid]; int bi = wbI[tid];
        #pragma unroll
        for (int w = 1; w < 4; ++w) {
            float od = wbD[w * 64 + tid]; int oi = wbI[w * 64 + tid];
            if (od < bd || (od == bd && oi < bi)) { bd = od; bi = oi; }
        }
        bidx[tid] = bi;
        out[IDX_OFF + n0 + tid] = (float)bi;
    }
    __syncthreads();

    // ---- epilogue: Q gather from PACKED f16 codebook (16B loads) + loss.
    float* qb = out + Q_OFF + b * ZSTRIDE_B + hw0;
    float lsum = 0.f;
    #pragma unroll
    for (int it = 0; it < 4; ++it) {
        int o = wv * 4 + it;
        int c = bidx[lane];
        int g = c >> 4, r = c & 15;
        int base = (g * 4 + (o >> 2)) * 512 + (o & 3) * 128 + r * 8;
        half8 hh = *(const half8*)&ehiP[base];   // 16B random L2 load
        half8 ll = *(const half8*)&eloP[base];
        half8 zh = *(const half8*)&xs_h[lane * XST + o * 8];
        half8 zl = *(const half8*)&xs_l[lane * XST + o * 8];
        #pragma unroll
        for (int jj = 0; jj < 8; ++jj) {
            float q  = (float)hh[jj] + (float)ll[jj];
            float zz = (float)zh[jj] + (float)zl[jj];
            qb[(o * 8 + jj) * HW + lane] = q;    // lanes consecutive: 256B coalesced
            float df = q - zz;
            lsum = fmaf(df, df, lsum);
        }
    }
    #pragma unroll
    for (int m = 32; m >= 1; m >>= 1) lsum += __shfl_xor(lsum, m, 64);
    if (lane == 0) wred[wv] = lsum;
    __syncthreads();
    if (tid == 0) unsafeAtomicAdd(lossAcc, wred[0] + wred[1] + wred[2] + wred[3]);
}

// ---------------------------------------------------------------------------
// k_ema2: PURE segment-sum, r8-exact (stable; LDS-atomic throughput
// ~3.5cyc/lane-op structural -- spread/native/one-hot-MFMA all failed to
// beat it, r6/r7/r9).
// 1024 blocks (32 b x 16 dchunk x 2 halves): plain LDS atomicAdd, unsafe
// global flush, rotated flush order. LDS 18KB -> up to 8 blocks/CU.
#define DC 8
__global__ __launch_bounds__(256) void k_ema2(const float* __restrict__ z,
                                              const float* __restrict__ out,
                                              float* __restrict__ enc,
                                              float* __restrict__ esum) {
    __shared__ float acc[DC][K];   // 16 KB
    __shared__ float cnt[K];       // 2 KB

    const int tid = threadIdx.x;
    const int half   = blockIdx.x & 1;
    const int dchunk = (blockIdx.x >> 1) & 15;
    const int b      = blockIdx.x >> 5;
    const int d0 = dchunk * DC;
    const bool doCnt = (dchunk == 0);

    for (int i = tid; i < DC * K; i += 256) ((float*)acc)[i] = 0.f;
    if (doCnt) for (int i = tid; i < K; i += 256) cnt[i] = 0.f;
    __syncthreads();

    const float* zb  = z + b * ZSTRIDE_B;
    const float* idp = out + IDX_OFF + b * HW;

    const int p0 = half * 2048;
    for (int t = p0; t < p0 + 2048; t += 1024) {
        const int p = t + 4 * tid;
        float4 iv = *(const float4*)(idp + p);
        int k0 = (int)iv.x;
        int k1 = (int)iv.y;
        int k2 = (int)iv.z;
        int k3 = (int)iv.w;
        if (doCnt) {
            atomicAdd(&cnt[k0], 1.f); atomicAdd(&cnt[k1], 1.f);
            atomicAdd(&cnt[k2], 1.f); atomicAdd(&cnt[k3], 1.f);
        }
        #pragma unroll
        for (int d = 0; d < DC; ++d) {
            float4 zv = *(const float4*)(zb + (d0 + d) * HW + p);
            atomicAdd(&acc[d][k0], zv.x);
            atomicAdd(&acc[d][k1], zv.y);
            atomicAdd(&acc[d][k2], zv.z);
            atomicAdd(&acc[d][k3], zv.w);
        }
    }
    __syncthreads();

    // flush: per-block rotated order so blocks don't march the same addresses
    const int rot = (blockIdx.x & 31) << 6;
    for (int i = tid; i < DC * K; i += 256) {
        int j = (i + rot) & (DC * K - 1);
        int d = j >> 9, k = j & 511;
        unsafeAtomicAdd(&esum[(d0 + d) * K + k], acc[d][k]);
    }
    if (doCnt) for (int i = tid; i < K; i += 256) unsafeAtomicAdd(&enc[i], cnt[i]);
}

// ---------------------------------------------------------------------------
// k_final: MERGED scalar + embedding update. 128 blocks x 512 threads.
// Every block redundantly computes the ncs/nn reduction; block d handles
// embedding row d; block 0 additionally writes ncs and loss.
__global__ __launch_bounds__(512) void k_final(const float* __restrict__ enc,
                                               const float* __restrict__ cs_in,
                                               const float* __restrict__ lossAcc,
                                               const float* __restrict__ esum,
                                               const float* __restrict__ eavg_in,
                                               float* __restrict__ out) {
    __shared__ float red[512];
    int k = threadIdx.x;
    int d = blockIdx.x;
    float ncs = fmaf(cs_in[k], 0.99f, 0.01f * enc[k]);
    red[k] = ncs;
    __syncthreads();
    for (int s = 256; s > 0; s >>= 1) {
        if (k < s) red[k] += red[k + s];
        __syncthreads();
    }
    float nn = fmaxf(red[0], 1e-5f);
    float cs = (ncs + 1e-5f) / (nn + (float)K * 1e-5f) * nn;
    float ea = fmaf(eavg_in[d * K + k], 0.99f, 0.01f * esum[d * K + k]);
    out[NEA_OFF + d * K + k] = ea;
    out[NEMB_OFF + d * K + k] = ea / cs;
    if (d == 0) {
        out[NCS_OFF + k] = ncs;
        if (k == 0) out[LOSS_OFF] = lossAcc[0] * 1.25f / 16777216.0f;
    }
}

// ---------------------------------------------------------------------------
extern "C" void kernel_launch(void* const* d_in, const int* in_sizes, int n_in,
                              void* d_out, int out_size, void* d_ws, size_t ws_size,
                              hipStream_t stream) {
    const float* z     = (const float*)d_in[0];
    const float* emb   = (const float*)d_in[1];
    const float* cs_in = (const float*)d_in[2];
    const float* eavg  = (const float*)d_in[3];
    float* out = (float*)d_out;
    float* wsF = (float*)d_ws;

    // ONE memset: LOSS + E2 + ENC + ESUM contiguous (66562 floats)
    hipMemsetAsync(wsF, 0, WS_ZERO_COUNT * sizeof(float), stream);

    k_prep<<<32, 256, 0, stream>>>(emb, (f16*)(wsF + WS_EHI), (f16*)(wsF + WS_ELO),
                                   wsF + WS_E2);
    k_assign<<<NPOS / 64, 256, 0, stream>>>(z,
                                            (const f16*)(wsF + WS_EHI),
                                            (const f16*)(wsF + WS_ELO),
                                            wsF + WS_E2, out, wsF + WS_LOSS);
    k_ema2<<<1024, 256, 0, stream>>>(z, out, wsF + WS_ENC, wsF + WS_ESUM);
    k_final<<<128, 512, 0, stream>>>(wsF + WS_ENC, cs_in, wsF + WS_LOSS,
                                     wsF + WS_ESUM, eavg, out);
}

// Round 14
// 283.456 us; speedup vs baseline: 1.1049x; 1.1049x over previous
//
#include <hip/hip_runtime.h>
#include <hip/hip_bf16.h>
#include <float.h>

typedef _Float16 f16;
typedef __attribute__((ext_vector_type(8))) _Float16 half8;
typedef __attribute__((ext_vector_type(4))) float floatx4;

// Problem constants
#define DIM   128
#define HW    4096
#define NPOS  131072
#define K     512
#define ZSTRIDE_B 524288

// Output layout (floats)
#define Q_OFF     0
#define LOSS_OFF  16777216
#define IDX_OFF   16777217
#define NEMB_OFF  16908289
#define NCS_OFF   16973825
#define NEA_OFF   16974337

// Workspace layout (floats): LOSS+E2+ENC+ESUM contiguous -> one memset.
// EHI/ELO past ESUM, 16B-aligned.
#define WS_LOSS  0
#define WS_E2    2
#define WS_ENC   514
#define WS_ESUM  1026          // 65536 floats, ends at 66562
#define WS_ZERO_COUNT 66562    // floats zeroed by the single upfront memset
#define WS_EHI   66564         // f16[K*DIM] = 32768 floats; byte ofs %16 == 0
#define WS_ELO   99332         // f16[K*DIM] = 32768 floats

#define XST 136   // xs row stride (f16): 128 d + 8 pad -> 272B, 16B-aligned, 2-way banks

// ---------------------------------------------------------------------------
// k_prep (r11 vectorized, measured-safe): thread = (code k, d-octet o):
// 8 coalesced f32 reads, ONE contiguous 16B half8 store each to hi/lo.
// Packed layout: idx(c,d) = (g*4+dc)*512 + quad*128 + r*8 + j, d = o*8+j
//   => base = (g*4+(o>>2))*512 + (o&3)*128 + r*8.
// e2 folded: per-thread 8-term partial, 16 atomics/address (native f32).
__global__ __launch_bounds__(256) void k_prep(const float* __restrict__ emb,
                                              f16* __restrict__ ehiP,
                                              f16* __restrict__ eloP,
                                              float* __restrict__ e2) {
    int lin = blockIdx.x * 256 + threadIdx.x;   // 8192 threads
    int o = lin >> 9, k = lin & 511;            // o = d-octet 0..15
    int g = k >> 4, r = k & 15;
    half8 hh, ll;
    float s = 0.f;
    #pragma unroll
    for (int j = 0; j < 8; ++j) {
        float v = emb[(o * 8 + j) * K + k];     // coalesced (lanes = consec k)
        f16 h = (f16)v;
        f16 l = (f16)(v - (float)h);
        hh[j] = h; ll[j] = l;
        s = fmaf(v, v, s);
    }
    int base = (g * 4 + (o >> 2)) * 512 + (o & 3) * 128 + r * 8;
    *(half8*)&ehiP[base] = hh;                  // 16B store
    *(half8*)&eloP[base] = ll;                  // 16B store
    unsafeAtomicAdd(&e2[k], s);                 // 16-way contention, native
}

// ---------------------------------------------------------------------------
// k_assign: r12-exact structure MINUS the Q/loss epilogue (r5-twin, idx only
// -- the split that produced the session-best totals r5/r6 ~291us).
// score = e2[c] - 2*dot(x,e); dot via 3-pass f16-split MFMA (hh + lh + hl).
// 4 code-chunks of 128 (acc[4][2] = 32 VGPR), (256,2) pin = 120-VGPR/4-wave
// point (r8/r12 proven optimal; r11/r13 proved any extra reg pressure for
// prefetch breaks it: 132 VGPR -> 3 waves -> 161us; 128+spill -> 121us).
__global__ __launch_bounds__(256, 2) void k_assign(const float* __restrict__ z,
                                                   const f16* __restrict__ ehiP,
                                                   const f16* __restrict__ eloP,
                                                   const float* __restrict__ e2,
                                                   float* __restrict__ out) {
    __shared__ f16 xs_h[64 * XST];
    __shared__ f16 xs_l[64 * XST];
    __shared__ float wbD[256];
    __shared__ int   wbI[256];

    const int tid  = threadIdx.x;
    const int lane = tid & 63;
    const int wv   = tid >> 6;
    const int n0   = blockIdx.x * 64;
    const int b    = n0 >> 12;
    const int hw0  = n0 & 4095;
    const float* zb = z + b * ZSTRIDE_B + hw0;
    const int l15  = lane & 15;
    const int quad = lane >> 4;

    // ---- stage X split (64 pos x 128 d): phase 1 = issue all 32 loads,
    // phase 2 = convert + packed u32 LDS writes. Static indexing throughout.
    float sv0[16], sv1[16];
    #pragma unroll
    for (int it = 0; it < 16; ++it) {
        int lin = tid + it * 256;
        int i  = lin & 63;          // position (lanes consecutive -> coalesced)
        int dp = lin >> 6;          // d-pair 0..63
        sv0[it] = zb[(2 * dp) * HW + i];
        sv1[it] = zb[(2 * dp + 1) * HW + i];
    }
    #pragma unroll
    for (int it = 0; it < 16; ++it) {
        int lin = tid + it * 256;
        int i  = lin & 63;
        int dp = lin >> 6;
        float v0 = sv0[it], v1 = sv1[it];
        f16 h0 = (f16)v0; f16 l0 = (f16)(v0 - (float)h0);
        f16 h1 = (f16)v1; f16 l1 = (f16)(v1 - (float)h1);
        union { f16 h[2]; unsigned int u; } ph, pl;
        ph.h[0] = h0; ph.h[1] = h1;
        pl.h[0] = l0; pl.h[1] = l1;
        *(unsigned int*)&xs_h[i * XST + 2 * dp] = ph.u;
        *(unsigned int*)&xs_l[i * XST + 2 * dp] = pl.u;
    }
    __syncthreads();

    float bestD[4][4];
    int   bestI[4][4];
    #pragma unroll
    for (int t = 0; t < 4; ++t)
        #pragma unroll
        for (int r = 0; r < 4; ++r) { bestD[t][r] = FLT_MAX; bestI[t][r] = 0x7fffffff; }

    const half8* gh = (const half8*)ehiP;
    const half8* gl = (const half8*)eloP;

    for (int cc = 0; cc < 4; ++cc) {       // 4 chunks x 128 codes
        floatx4 acc[4][2];
        #pragma unroll
        for (int t = 0; t < 4; ++t)
            #pragma unroll
            for (int nt = 0; nt < 2; ++nt) acc[t][nt] = (floatx4){0.f, 0.f, 0.f, 0.f};

        for (int dc = 0; dc < 4; ++dc) {
            // A fragments: A[m = t*16 + (lane&15)][k = quad*8 + j]
            half8 ah[4], al[4];
            #pragma unroll
            for (int t = 0; t < 4; ++t) {
                int off = (t * 16 + l15) * XST + dc * 32 + quad * 8;
                ah[t] = *(const half8*)&xs_h[off];
                al[t] = *(const half8*)&xs_l[off];
            }
            #pragma unroll
            for (int nt = 0; nt < 2; ++nt) {
                // B fragment: wave-contiguous 1KB load from packed codebook
                int g  = cc * 8 + wv * 2 + nt;      // 16-code group
                int bi = (g * 4 + dc) * 64 + lane;
                half8 bh = gh[bi];
                half8 bl = gl[bi];
                #pragma unroll
                for (int t = 0; t < 4; ++t) {
                    acc[t][nt] = __builtin_amdgcn_mfma_f32_16x16x32_f16(ah[t], bh, acc[t][nt], 0, 0, 0);
                    acc[t][nt] = __builtin_amdgcn_mfma_f32_16x16x32_f16(al[t], bh, acc[t][nt], 0, 0, 0);
                    acc[t][nt] = __builtin_amdgcn_mfma_f32_16x16x32_f16(ah[t], bl, acc[t][nt], 0, 0, 0);
                }
            }
        }
        // fold scores into best (codes ascend across cc,nt for fixed lane -> strict <)
        #pragma unroll
        for (int nt = 0; nt < 2; ++nt) {
            int c = cc * 128 + wv * 32 + nt * 16 + l15;
            float ee = e2[c];
            #pragma unroll
            for (int t = 0; t < 4; ++t)
                #pragma unroll
                for (int r = 0; r < 4; ++r) {
                    float s = fmaf(-2.f, acc[t][nt][r], ee);
                    if (s < bestD[t][r]) { bestD[t][r] = s; bestI[t][r] = c; }
                }
        }
    }

    // reduce across the 16 lanes holding different codes for the same rows
    #pragma unroll
    for (int mask = 1; mask <= 8; mask <<= 1) {
        #pragma unroll
        for (int t = 0; t < 4; ++t)
            #pragma unroll
            for (int r = 0; r < 4; ++r) {
                float od = __shfl_xor(bestD[t][r], mask, 64);
                int   oi = __shfl_xor(bestI[t][r], mask, 64);
                if (od < bestD[t][r] || (od == bestD[t][r] && oi < bestI[t][r])) {
                    bestD[t][r] = od; bestI[t][r] = oi;
                }
            }
    }
    if (l15 == 0) {
        #pragma unroll
        for (int t = 0; t < 4; ++t)
            #pragma unroll
            for (int r = 0; r < 4; ++r) {
                int m = t * 16 + quad * 4 + r;   // C layout: row=(lane>>4)*4+reg
                wbD[wv * 64 + m] = bestD[t][r];
                wbI[wv * 64 + m] = bestI[t][r];
            }
    }
    __syncthreads();
    if (tid < 64) {
        float bd = wbD[tid]; int bi = wbI[tid];
        #pragma unroll
        for (int w = 1; w < 4; ++w) {
            float od = wbD[w * 64 + tid]; int oi = wbI[w * 64 + tid];
            if (od < bd || (od == bd && oi < bi)) { bd = od; bi = oi; }
        }
        out[IDX_OFF + n0 + tid] = (float)bi;
    }
}

// ---------------------------------------------------------------------------
// k_ema2: r5-exact Q-fused version (session-best k_ema2-with-Q: 105us).
// LDS-privatized segment sums + FUSED quantized-output/loss epilogue.
// 1024 blocks (32 b x 16 dchunk x 2 HW-halves). Block stages its 8 emb rows
// (16KB) in LDS -> Q gather is an LDS lookup; Q written coalesced float4
// alongside the z stream. Global flush/loss use native unsafe atomics.
#define DC 8
__global__ __launch_bounds__(256) void k_ema2(const float* __restrict__ z,
                                              const float* __restrict__ emb,
                                              float* __restrict__ out,
                                              float* __restrict__ enc,
                                              float* __restrict__ esum,
                                              float* __restrict__ lossAcc) {
    __shared__ float acc[DC][K];   // 16 KB
    __shared__ float embs[DC][K];  // 16 KB
    __shared__ float cnt[K];       // 2 KB
    __shared__ float wred[4];

    const int tid = threadIdx.x;
    const int lane = tid & 63;
    const int wv = tid >> 6;
    const int half   = blockIdx.x & 1;
    const int dchunk = (blockIdx.x >> 1) & 15;
    const int b      = blockIdx.x >> 5;
    const int d0 = dchunk * DC;
    const bool doCnt = (dchunk == 0);

    for (int i = tid; i < DC * K; i += 256) {
        ((float*)acc)[i] = 0.f;
        ((float*)embs)[i] = emb[d0 * K + i];   // coalesced 16KB stage
    }
    if (doCnt) for (int i = tid; i < K; i += 256) cnt[i] = 0.f;
    __syncthreads();

    const float* zb  = z + b * ZSTRIDE_B;
    const float* idp = out + IDX_OFF + b * HW;
    float* qb = out + Q_OFF + b * ZSTRIDE_B;
    float lsum = 0.f;

    const int p0 = half * 2048;
    for (int t = p0; t < p0 + 2048; t += 1024) {
        const int p = t + 4 * tid;
        float4 iv = *(const float4*)(idp + p);
        int k0 = (int)iv.x;
        int k1 = (int)iv.y;
        int k2 = (int)iv.z;
        int k3 = (int)iv.w;
        if (doCnt) {
            atomicAdd(&cnt[k0], 1.f); atomicAdd(&cnt[k1], 1.f);
            atomicAdd(&cnt[k2], 1.f); atomicAdd(&cnt[k3], 1.f);
        }
        #pragma unroll
        for (int d = 0; d < DC; ++d) {
            float4 zv = *(const float4*)(zb + (d0 + d) * HW + p);
            atomicAdd(&acc[d][k0], zv.x);
            atomicAdd(&acc[d][k1], zv.y);
            atomicAdd(&acc[d][k2], zv.z);
            atomicAdd(&acc[d][k3], zv.w);
            float4 qv;
            qv.x = embs[d][k0]; qv.y = embs[d][k1];
            qv.z = embs[d][k2]; qv.w = embs[d][k3];
            *(float4*)(qb + (d0 + d) * HW + p) = qv;
            float dx = qv.x - zv.x; lsum = fmaf(dx, dx, lsum);
            float dy = qv.y - zv.y; lsum = fmaf(dy, dy, lsum);
            float dz2 = qv.z - zv.z; lsum = fmaf(dz2, dz2, lsum);
            float dw = qv.w - zv.w; lsum = fmaf(dw, dw, lsum);
        }
    }

    // loss partial: wave reduce -> LDS -> one native atomic per block
    #pragma unroll
    for (int m = 32; m >= 1; m >>= 1) lsum += __shfl_xor(lsum, m, 64);
    if (lane == 0) wred[wv] = lsum;
    __syncthreads();   // also guarantees all LDS atomics complete before flush
    if (tid == 0) unsafeAtomicAdd(lossAcc, wred[0] + wred[1] + wred[2] + wred[3]);

    // flush: per-block rotated order so blocks don't march the same addresses
    const int rot = (blockIdx.x & 31) << 6;
    for (int i = tid; i < DC * K; i += 256) {
        int j = (i + rot) & (DC * K - 1);
        int d = j >> 9, k = j & 511;
        unsafeAtomicAdd(&esum[(d0 + d) * K + k], acc[d][k]);
    }
    if (doCnt) for (int i = tid; i < K; i += 256) unsafeAtomicAdd(&enc[i], cnt[i]);
}

// ---------------------------------------------------------------------------
// k_final: MERGED scalar + embedding update. 128 blocks x 512 threads.
// Every block redundantly computes the ncs/nn reduction; block d handles
// embedding row d; block 0 additionally writes ncs and loss.
__global__ __launch_bounds__(512) void k_final(const float* __restrict__ enc,
                                               const float* __restrict__ cs_in,
                                               const float* __restrict__ lossAcc,
                                               const float* __restrict__ esum,
                                               const float* __restrict__ eavg_in,
                                               float* __restrict__ out) {
    __shared__ float red[512];
    int k = threadIdx.x;
    int d = blockIdx.x;
    float ncs = fmaf(cs_in[k], 0.99f, 0.01f * enc[k]);
    red[k] = ncs;
    __syncthreads();
    for (int s = 256; s > 0; s >>= 1) {
        if (k < s) red[k] += red[k + s];
        __syncthreads();
    }
    float nn = fmaxf(red[0], 1e-5f);
    float cs = (ncs + 1e-5f) / (nn + (float)K * 1e-5f) * nn;
    float ea = fmaf(eavg_in[d * K + k], 0.99f, 0.01f * esum[d * K + k]);
    out[NEA_OFF + d * K + k] = ea;
    out[NEMB_OFF + d * K + k] = ea / cs;
    if (d == 0) {
        out[NCS_OFF + k] = ncs;
        if (k == 0) out[LOSS_OFF] = lossAcc[0] * 1.25f / 16777216.0f;
    }
}

// ---------------------------------------------------------------------------
extern "C" void kernel_launch(void* const* d_in, const int* in_sizes, int n_in,
                              void* d_out, int out_size, void* d_ws, size_t ws_size,
                              hipStream_t stream) {
    const float* z     = (const float*)d_in[0];
    const float* emb   = (const float*)d_in[1];
    const float* cs_in = (const float*)d_in[2];
    const float* eavg  = (const float*)d_in[3];
    float* out = (float*)d_out;
    float* wsF = (float*)d_ws;

    // ONE memset: LOSS + E2 + ENC + ESUM contiguous (66562 floats)
    hipMemsetAsync(wsF, 0, WS_ZERO_COUNT * sizeof(float), stream);

    k_prep<<<32, 256, 0, stream>>>(emb, (f16*)(wsF + WS_EHI), (f16*)(wsF + WS_ELO),
                                   wsF + WS_E2);
    k_assign<<<NPOS / 64, 256, 0, stream>>>(z,
                                            (const f16*)(wsF + WS_EHI),
                                            (const f16*)(wsF + WS_ELO),
                                            wsF + WS_E2, out);
    k_ema2<<<1024, 256, 0, stream>>>(z, emb, out, wsF + WS_ENC, wsF + WS_ESUM,
                                     wsF + WS_LOSS);
    k_final<<<128, 512, 0, stream>>>(wsF + WS_ENC, cs_in, wsF + WS_LOSS,
                                     wsF + WS_ESUM, eavg, out);
}